// Round 6
// baseline (313.071 us; speedup 1.0000x reference)
//
#include <hip/hip_runtime.h>
#include <hip/hip_bf16.h>

#define NN 50000
#define EE 800000
#define DD 256
#define BF 128      // B*F
#define HC 96       // H*B*A
#define GG 64
#define NT 14       // (BF+HC)/16
#define KCN 8       // 256/32 k-chunks
#define NB 49       // ceil(NN/1024)
#define RS 3125     // node-range size (NN/16)
#define RC 16       // node ranges
#define CS 12500    // edges per chunk (EE/64)
#define CC 64       // edge chunks
#define SL 8        // stats slices per graph

typedef short s16x8 __attribute__((ext_vector_type(8)));
typedef float f32x4 __attribute__((ext_vector_type(4)));

static __device__ __forceinline__ float b2f(unsigned u) {
    unsigned x = u << 16;
    float f;
    __builtin_memcpy(&f, &x, 4);
    return f;
}
static __device__ __forceinline__ unsigned short f2b(float f) {
    unsigned x;
    __builtin_memcpy(&x, &f, 4);
    unsigned lsb = (x >> 16) & 1u;
    x += 0x7fffu + lsb;           // round-to-nearest-even
    return (unsigned short)(x >> 16);
}
static __device__ __forceinline__ unsigned pack_trunc(float lo, float hi) {
    unsigned ulo, uhi;
    __builtin_memcpy(&ulo, &lo, 4);
    __builtin_memcpy(&uhi, &hi, 4);
    return (ulo >> 16) | (uhi & 0xffff0000u);
}

// ---------------- setup: dtype detect + param convert + goff ----------------
__global__ void k_setup(const unsigned short* node_u16, int* flag,
                        const void* bcomb, const void* cbias, const void* gw,
                        const void* gb, const void* gms,
                        float* bcombF, float* cbiasF, float* gwF, float* gbF, float* gmsF,
                        const int* batch, int* goff) {
    if (blockIdx.x == 0) {
        __shared__ int cnt;
        if (threadIdx.x == 0) cnt = 0;
        __syncthreads();
        int local = 0;
        #pragma unroll
        for (int j = 0; j < 4; j++) {
            int idx = 2 * (threadIdx.x * 4 + j);   // EVEN u16 of f32 = mantissa garbage
            unsigned short u = node_u16[idx];
            int e = (u >> 7) & 0xFF;
            if (e < 100 || e > 140) local++;
        }
        atomicAdd(&cnt, local);
        __syncthreads();
        int isf = (cnt > 256) ? 1 : 0;
        if (threadIdx.x == 0) flag[0] = isf;
        int d = threadIdx.x;
        auto rd = [&](const void* p, int i) -> float {
            return isf ? ((const float*)p)[i] : b2f(((const unsigned short*)p)[i]);
        };
        if (d < HC) bcombF[d] = rd(bcomb, d);
        cbiasF[d] = rd(cbias, d);
        gwF[d] = rd(gw, d);
        gbF[d] = rd(gb, d);
        gmsF[d] = rd(gms, d);
    } else {
        int g = threadIdx.x;
        if (g > GG) return;
        int lo = 0, hi = NN;
        while (lo < hi) { int mid = (lo + hi) >> 1; if (batch[mid] < g) lo = mid + 1; else hi = mid; }
        goff[g] = lo;
    }
}

// ---------------- per-(chunk,range) LDS histogram -> partial[c][n] ----------------
__global__ __launch_bounds__(256) void k_ehist(const int* ei, int* partial) {
    __shared__ int hist[RS];
    int c = blockIdx.x, r = blockIdx.y;
    for (int i = threadIdx.x; i < RS; i += 256) hist[i] = 0;
    __syncthreads();
    int base = r * RS;
    const int* dstp = ei + EE + (size_t)c * CS;
    for (int i = threadIdx.x; i < CS; i += 256) {
        int d = dstp[i] - base;
        if ((unsigned)d < RS) atomicAdd(&hist[d], 1);
    }
    __syncthreads();
    int* o = partial + (size_t)c * NN + base;
    for (int i = threadIdx.x; i < RS; i += 256) o[i] = hist[i];
}

// ---------------- per-node exclusive scan over chunks + deg ----------------
__global__ void k_colscan(int* partial, int* deg) {
    int n = blockIdx.x * 256 + threadIdx.x;
    if (n >= NN) return;
    int run = 0;
    for (int c = 0; c < CC; c++) {
        size_t idx = (size_t)c * NN + n;
        int v = partial[idx];
        partial[idx] = run;
        run += v;
    }
    deg[n] = run + 1;   // +1 self-loop
}

// ---------------- block scan for row_off ----------------
__global__ void k_scan1(const int* deg, int* bsum) {
    __shared__ int lds[256];
    int b = blockIdx.x, t = threadIdx.x;
    int base = b * 1024 + t * 4;
    int s = 0;
    #pragma unroll
    for (int j = 0; j < 4; j++) { int idx = base + j; if (idx < NN) s += deg[idx]; }
    lds[t] = s; __syncthreads();
    for (int ofs = 128; ofs > 0; ofs >>= 1) {
        if (t < ofs) lds[t] += lds[t + ofs];
        __syncthreads();
    }
    if (t == 0) bsum[b] = lds[0];
}

__global__ void k_scan2(const int* bsum, int* bpre, int* row_off) {
    if (threadIdx.x == 0) {
        int r = 0;
        for (int i = 0; i < NB; i++) { bpre[i] = r; r += bsum[i]; }
        row_off[NN] = r;
    }
}

__global__ void k_scan3(const int* deg, const int* bpre, int* row_off, float* dinv, int* csr) {
    __shared__ int lds[256];
    int b = blockIdx.x, t = threadIdx.x;
    int base = b * 1024 + t * 4;
    int d[4]; int s = 0;
    #pragma unroll
    for (int j = 0; j < 4; j++) { int idx = base + j; d[j] = (idx < NN) ? deg[idx] : 0; s += d[j]; }
    lds[t] = s; __syncthreads();
    for (int ofs = 1; ofs < 256; ofs <<= 1) {
        int add = (t >= ofs) ? lds[t - ofs] : 0;
        __syncthreads();
        lds[t] += add;
        __syncthreads();
    }
    int excl = lds[t] - s + bpre[b];
    #pragma unroll
    for (int j = 0; j < 4; j++) {
        int idx = base + j;
        if (idx < NN) {
            row_off[idx] = excl;
            csr[excl] = idx;             // self-loop in slot 0 of each row
            excl += d[j];
            dinv[idx] = rsqrtf((float)deg[idx]);
        }
    }
}

// ---------------- deterministic scatter: LDS cursors only ----------------
__global__ __launch_bounds__(256) void k_escatter(const int* ei, const int* row_off,
                                                  const int* partial, int* csr) {
    __shared__ int cur[RS];
    int c = blockIdx.x, r = blockIdx.y;
    int base = r * RS;
    const int* po = partial + (size_t)c * NN + base;
    const int* ro = row_off + base;
    for (int i = threadIdx.x; i < RS; i += 256) cur[i] = ro[i] + 1 + po[i];
    __syncthreads();
    const int* srcp = ei + (size_t)c * CS;
    const int* dstp = ei + EE + (size_t)c * CS;
    for (int i = threadIdx.x; i < CS; i += 256) {
        int d = dstp[i] - base;
        int s = srcp[i];                 // coalesced unconditional read
        if ((unsigned)d < RS) {
            int slot = atomicAdd(&cur[d], 1);
            csr[slot] = s;
        }
    }
}

// ---------------- pack W (bases|comb) into MFMA B-fragment layout ----------------
__global__ void k_pack(const int* flag, const void* Wb, const void* Wc, unsigned short* wpack) {
    int t = blockIdx.x, kc = blockIdx.y, lane = threadIdx.x;
    int isf = flag[0];
    int n = t * 16 + (lane & 15);
    int kb = kc * 32 + (lane >> 4) * 8;
    unsigned short* o = wpack + (size_t)(((t * KCN) + kc) * 64 + lane) * 8;
    #pragma unroll
    for (int j = 0; j < 8; j++) {
        int k = kb + j;
        int src = (n < BF) ? (k * BF + n) : (k * HC + (n - BF));
        const void* W = (n < BF) ? Wb : Wc;
        o[j] = isf ? f2b(((const float*)W)[src]) : ((const unsigned short*)W)[src];
    }
}

// ---------------- fused GEMM -> bases[N,128] bf16 + comb[N,96] f32 ----------------
__global__ __launch_bounds__(256) void k_gemm(const int* flag, const void* node,
                                              const unsigned short* wpack, const float* bcombF,
                                              unsigned short* bases, float* comb) {
    int wv = threadIdx.x >> 6, lane = threadIdx.x & 63;
    int row0 = blockIdx.x * 64 + wv * 16;
    int m = row0 + (lane & 15);
    int mc = m < NN ? m : NN - 1;
    int kg = lane >> 4;
    int isf = flag[0];
    const s16x8* bp = reinterpret_cast<const s16x8*>(wpack);
    f32x4 acc[NT];
    #pragma unroll
    for (int t = 0; t < NT; t++) acc[t] = (f32x4){0.f, 0.f, 0.f, 0.f};
    if (isf) {
        const float* nf = (const float*)node + (size_t)mc * DD;
        for (int kc = 0; kc < KCN; kc++) {
            const f32x4* src = reinterpret_cast<const f32x4*>(nf + kc * 32 + kg * 8);
            f32x4 x0 = src[0], x1 = src[1];
            union { s16x8 v; unsigned u[4]; } a;
            a.u[0] = pack_trunc(x0[0], x0[1]);
            a.u[1] = pack_trunc(x0[2], x0[3]);
            a.u[2] = pack_trunc(x1[0], x1[1]);
            a.u[3] = pack_trunc(x1[2], x1[3]);
            #pragma unroll
            for (int t = 0; t < NT; t++) {
                s16x8 b = bp[(size_t)(t * KCN + kc) * 64 + lane];
                acc[t] = __builtin_amdgcn_mfma_f32_16x16x32_bf16(a.v, b, acc[t], 0, 0, 0);
            }
        }
    } else {
        const s16x8* ap = reinterpret_cast<const s16x8*>(node);
        for (int kc = 0; kc < KCN; kc++) {
            s16x8 a = ap[(size_t)mc * 32 + kc * 4 + kg];
            #pragma unroll
            for (int t = 0; t < NT; t++) {
                s16x8 b = bp[(size_t)(t * KCN + kc) * 64 + lane];
                acc[t] = __builtin_amdgcn_mfma_f32_16x16x32_bf16(a, b, acc[t], 0, 0, 0);
            }
        }
    }
    int colb = lane & 15;
    #pragma unroll
    for (int t = 0; t < NT; t++) {
        int nc = t * 16 + colb;
        #pragma unroll
        for (int i = 0; i < 4; i++) {
            int r = row0 + kg * 4 + i;
            if (r < NN) {
                float v = acc[t][i];
                if (nc < BF) bases[(size_t)r * BF + nc] = f2b(v);
                else comb[(size_t)r * HC + (nc - BF)] = v + bcombF[nc - BF];
            }
        }
    }
}

// ---------------- per-node aggregation + einsum -> h[N,256] bf16 (ws) ----------------
__global__ __launch_bounds__(256) void k_agg(const unsigned short* bases,
                                             const float* comb, const float* dinv,
                                             const int* row_off, const int* csr,
                                             const float* cbiasF, unsigned short* h) {
    __shared__ float2 lds[4][3][64];
    int wv = threadIdx.x >> 6, lane = threadIdx.x & 63;
    int v = blockIdx.x * 4 + wv;          // NN % 4 == 0
    int r0 = row_off[v], r1 = row_off[v + 1];
    float dv = dinv[v];
    const unsigned* bp = reinterpret_cast<const unsigned*>(bases);
    float sy0 = 0.f, sy1 = 0.f, su0 = 0.f, su1 = 0.f;
    float mx0 = -3.4e38f, mx1 = -3.4e38f;
    for (int base = r0; base < r1; base += 64) {
        int nload = r1 - base; if (nload > 64) nload = 64;
        int sidx = 0; float wgt = 0.f;
        if (lane < nload) { sidx = csr[base + lane]; wgt = dinv[sidx] * dv; }
        int j = 0;
        for (; j + 4 <= nload; j += 4) {
            int s0 = __shfl(sidx, j),     s1 = __shfl(sidx, j + 1);
            int s2 = __shfl(sidx, j + 2), s3 = __shfl(sidx, j + 3);
            float w0 = __shfl(wgt, j),     w1 = __shfl(wgt, j + 1);
            float w2 = __shfl(wgt, j + 2), w3 = __shfl(wgt, j + 3);
            unsigned g0 = bp[(size_t)s0 * 64 + lane];
            unsigned g1 = bp[(size_t)s1 * 64 + lane];
            unsigned g2 = bp[(size_t)s2 * 64 + lane];
            unsigned g3 = bp[(size_t)s3 * 64 + lane];
            float a, b;
            a = b2f(g0 & 0xffffu); b = b2f(g0 >> 16);
            sy0 += w0 * a; sy1 += w0 * b; su0 += a; su1 += b; mx0 = fmaxf(mx0, a); mx1 = fmaxf(mx1, b);
            a = b2f(g1 & 0xffffu); b = b2f(g1 >> 16);
            sy0 += w1 * a; sy1 += w1 * b; su0 += a; su1 += b; mx0 = fmaxf(mx0, a); mx1 = fmaxf(mx1, b);
            a = b2f(g2 & 0xffffu); b = b2f(g2 >> 16);
            sy0 += w2 * a; sy1 += w2 * b; su0 += a; su1 += b; mx0 = fmaxf(mx0, a); mx1 = fmaxf(mx1, b);
            a = b2f(g3 & 0xffffu); b = b2f(g3 >> 16);
            sy0 += w3 * a; sy1 += w3 * b; su0 += a; su1 += b; mx0 = fmaxf(mx0, a); mx1 = fmaxf(mx1, b);
        }
        for (; j < nload; j++) {
            int s0 = __shfl(sidx, j); float w0 = __shfl(wgt, j);
            unsigned g0 = bp[(size_t)s0 * 64 + lane];
            float a = b2f(g0 & 0xffffu), b = b2f(g0 >> 16);
            sy0 += w0 * a; sy1 += w0 * b; su0 += a; su1 += b; mx0 = fmaxf(mx0, a); mx1 = fmaxf(mx1, b);
        }
    }
    lds[wv][0][lane] = (float2){sy0, sy1};
    lds[wv][1][lane] = (float2){su0, su1};
    lds[wv][2][lane] = (float2){mx0, mx1};
    __syncthreads();
    const float* P0 = (const float*)&lds[wv][0][0];
    const float* P1 = (const float*)&lds[wv][1][0];
    const float* P2 = (const float*)&lds[wv][2][0];
    int d0 = lane * 4;
    int hh = d0 >> 5;
    float cb[12];
    #pragma unroll
    for (int k = 0; k < 12; k++) cb[k] = comb[(size_t)v * HC + hh * 12 + k];
    union { unsigned short e[4]; uint2 u; } o;
    #pragma unroll
    for (int i = 0; i < 4; i++) {
        int d = d0 + i, f = d & 31;
        float acc = cbiasF[d];
        #pragma unroll
        for (int k = 0; k < 12; k++) {
            int a = k >> 2, b = k & 3;
            const float* P = (a == 0) ? P0 : ((a == 1) ? P1 : P2);
            acc += cb[k] * P[b * 32 + f];
        }
        o.e[i] = f2b(acc);
    }
    reinterpret_cast<uint2*>(h)[(size_t)v * 64 + lane] = o.u;
}

// ---------------- GraphNorm stats pass 1: atomic-free sliced reduction ----------------
__global__ void k_stats1(const unsigned short* h, const int* goff, float* sstat) {
    int g = blockIdx.x, s = blockIdx.y, t = threadIdx.x;
    int v0 = goff[g], v1 = goff[g + 1];
    float sum = 0.f, sq = 0.f;
    for (int v = v0 + s; v < v1; v += SL) {
        float x = b2f(h[(size_t)v * DD + t]);
        sum += x; sq += x * x;
    }
    size_t o = ((size_t)(g * SL + s)) * (2 * DD);
    sstat[o + t] = sum;
    sstat[o + DD + t] = sq;
}

// ---------------- GraphNorm stats pass 2: fold slices, compute scale/shift ----------------
__global__ void k_stats2(const float* sstat, const int* goff,
                         const float* gwF, const float* gbF, const float* gmsF,
                         float* sA, float* sB) {
    int g = blockIdx.x, d = threadIdx.x;
    float sum = 0.f, sq = 0.f;
    #pragma unroll
    for (int s = 0; s < SL; s++) {
        size_t o = ((size_t)(g * SL + s)) * (2 * DD);
        sum += sstat[o + d];
        sq  += sstat[o + DD + d];
    }
    int c = goff[g + 1] - goff[g];
    float cnt = (float)(c > 1 ? c : 1);
    float mu = sum / cnt;
    float m2 = sq / cnt;
    float al = gmsF[d];
    float var = m2 - mu * mu * (2.f * al - al * al);   // E[(h-al*mu)^2]
    float rstd = rsqrtf(var + 1e-5f);
    float sa = gwF[d] * rstd;
    sA[g * DD + d] = sa;
    sB[g * DD + d] = gbF[d] - sa * al * mu;
}

// ---------------- final normalize + ReLU -> d_out ----------------
__global__ void k_out(const int* flag, const unsigned short* h, const int* batch,
                      const float* sA, const float* sB, void* out) {
    int tid = blockIdx.x * 256 + threadIdx.x;
    int v = tid >> 6, q = tid & 63;
    if (v >= NN) return;
    int g = batch[v];
    uint2 xr = reinterpret_cast<const uint2*>(h)[(size_t)v * 64 + q];
    f32x4 a = reinterpret_cast<const f32x4*>(sA)[g * 64 + q];
    f32x4 b = reinterpret_cast<const f32x4*>(sB)[g * 64 + q];
    float x0 = b2f(xr.x & 0xffffu), x1 = b2f(xr.x >> 16);
    float x2 = b2f(xr.y & 0xffffu), x3 = b2f(xr.y >> 16);
    float y0 = fmaxf(x0 * a[0] + b[0], 0.f);
    float y1 = fmaxf(x1 * a[1] + b[1], 0.f);
    float y2 = fmaxf(x2 * a[2] + b[2], 0.f);
    float y3 = fmaxf(x3 * a[3] + b[3], 0.f);
    if (flag[0]) {
        f32x4 y = {y0, y1, y2, y3};
        reinterpret_cast<f32x4*>(out)[(size_t)v * 64 + q] = y;
    } else {
        union { unsigned short e[4]; uint2 u; } o;
        o.e[0] = f2b(y0); o.e[1] = f2b(y1); o.e[2] = f2b(y2); o.e[3] = f2b(y3);
        reinterpret_cast<uint2*>(out)[(size_t)v * 64 + q] = o.u;
    }
}

extern "C" void kernel_launch(void* const* d_in, const int* in_sizes, int n_in,
                              void* d_out, int out_size, void* d_ws, size_t ws_size,
                              hipStream_t stream) {
    const void* node  = d_in[0];
    const void* Wb    = d_in[2];
    const void* Wc    = d_in[3];
    const void* bcomb = d_in[4];
    const void* cbias = d_in[5];
    const void* gw    = d_in[6];
    const void* gb    = d_in[7];
    const void* gms   = d_in[8];
    const int* ei     = (const int*)d_in[9];
    const int* batch  = (const int*)d_in[10];

    char* w = (char*)d_ws;
    size_t off = 0;
    auto alloc = [&](size_t bytes) -> void* {
        off = (off + 255) & ~(size_t)255;
        void* p = w + off;
        off += bytes;
        return p;
    };
    unsigned short* bases = (unsigned short*)alloc((size_t)NN * BF * 2);
    float* comb    = (float*)alloc((size_t)NN * HC * 4);
    unsigned short* h = (unsigned short*)alloc((size_t)NN * DD * 2);
    int*   csr     = (int*)alloc((size_t)(EE + NN) * 4);
    int*   partial = (int*)alloc((size_t)CC * NN * 4);
    int*   deg     = (int*)alloc((size_t)NN * 4);
    float* dinv    = (float*)alloc((size_t)NN * 4);
    int*   row_off = (int*)alloc((size_t)(NN + 1) * 4);
    int*   bsum    = (int*)alloc((size_t)NB * 4);
    int*   bpre    = (int*)alloc((size_t)NB * 4);
    int*   goff    = (int*)alloc((size_t)(GG + 1) * 4);
    float* sstat   = (float*)alloc((size_t)GG * SL * 2 * DD * 4);
    float* sA      = (float*)alloc((size_t)GG * DD * 4);
    float* sB      = (float*)alloc((size_t)GG * DD * 4);
    unsigned short* wpack = (unsigned short*)alloc((size_t)NT * KCN * 64 * 8 * 2);
    int*   flag    = (int*)alloc(256);
    float* bcombF  = (float*)alloc(HC * 4);
    float* cbiasF  = (float*)alloc(DD * 4);
    float* gwF     = (float*)alloc(DD * 4);
    float* gbF     = (float*)alloc(DD * 4);
    float* gmsF    = (float*)alloc(DD * 4);

    k_setup<<<2, 256, 0, stream>>>((const unsigned short*)node, flag, bcomb, cbias, gw, gb, gms,
                                   bcombF, cbiasF, gwF, gbF, gmsF, batch, goff);
    k_ehist<<<dim3(CC, RC), 256, 0, stream>>>(ei, partial);
    k_colscan<<<(NN + 255) / 256, 256, 0, stream>>>(partial, deg);
    k_scan1<<<NB, 256, 0, stream>>>(deg, bsum);
    k_scan2<<<1, 64, 0, stream>>>(bsum, bpre, row_off);
    k_scan3<<<NB, 256, 0, stream>>>(deg, bpre, row_off, dinv, csr);
    k_escatter<<<dim3(CC, RC), 256, 0, stream>>>(ei, row_off, partial, csr);
    k_pack<<<dim3(NT, KCN), 64, 0, stream>>>(flag, Wb, Wc, wpack);
    k_gemm<<<(NN + 63) / 64, 256, 0, stream>>>(flag, node, wpack, bcombF, bases, comb);
    k_agg<<<NN / 4, 256, 0, stream>>>(bases, comb, dinv, row_off, csr, cbiasF, h);
    k_stats1<<<dim3(GG, SL), 256, 0, stream>>>(h, goff, sstat);
    k_stats2<<<GG, 256, 0, stream>>>(sstat, goff, gwF, gbF, gmsF, sA, sB);
    k_out<<<(NN * 64 + 255) / 256, 256, 0, stream>>>(flag, h, batch, sA, sB, d_out);
}

// Round 7
// 271.178 us; speedup vs baseline: 1.1545x; 1.1545x over previous
//
#include <hip/hip_runtime.h>
#include <hip/hip_bf16.h>

#define NN 50000
#define EE 800000
#define DD 256
#define BF 128      // B*F
#define HC 96       // H*B*A
#define GG 64
#define NT 14       // (BF+HC)/16
#define KCN 8       // 256/32 k-chunks
#define RC 98       // node ranges (512 nodes each)
#define RSH 9       // range shift: RS = 512
#define RSZ 512
#define CC 256      // edge chunks
#define CS 3125     // edges per chunk (EE/256)
#define CAP 10240   // bucket capacity per range (avg 8192, +22 sigma)
#define SL 8        // stats slices per graph
#define STG 10752   // CAP + RSZ

typedef short s16x8 __attribute__((ext_vector_type(8)));
typedef float f32x4 __attribute__((ext_vector_type(4)));

static __device__ __forceinline__ float b2f(unsigned u) {
    unsigned x = u << 16;
    float f;
    __builtin_memcpy(&f, &x, 4);
    return f;
}
static __device__ __forceinline__ unsigned short f2b(float f) {
    unsigned x;
    __builtin_memcpy(&x, &f, 4);
    unsigned lsb = (x >> 16) & 1u;
    x += 0x7fffu + lsb;           // round-to-nearest-even
    return (unsigned short)(x >> 16);
}
static __device__ __forceinline__ unsigned pack_trunc(float lo, float hi) {
    unsigned ulo, uhi;
    __builtin_memcpy(&ulo, &lo, 4);
    __builtin_memcpy(&uhi, &hi, 4);
    return (ulo >> 16) | (uhi & 0xffff0000u);
}

// ---------------- setup: dtype detect + param convert + goff ----------------
__global__ void k_setup(const unsigned short* node_u16, int* flag,
                        const void* bcomb, const void* cbias, const void* gw,
                        const void* gb, const void* gms,
                        float* bcombF, float* cbiasF, float* gwF, float* gbF, float* gmsF,
                        const int* batch, int* goff) {
    if (blockIdx.x == 0) {
        __shared__ int cnt;
        if (threadIdx.x == 0) cnt = 0;
        __syncthreads();
        int local = 0;
        #pragma unroll
        for (int j = 0; j < 4; j++) {
            int idx = 2 * (threadIdx.x * 4 + j);   // EVEN u16 of f32 = mantissa garbage
            unsigned short u = node_u16[idx];
            int e = (u >> 7) & 0xFF;
            if (e < 100 || e > 140) local++;
        }
        atomicAdd(&cnt, local);
        __syncthreads();
        int isf = (cnt > 256) ? 1 : 0;
        if (threadIdx.x == 0) flag[0] = isf;
        int d = threadIdx.x;
        auto rd = [&](const void* p, int i) -> float {
            return isf ? ((const float*)p)[i] : b2f(((const unsigned short*)p)[i]);
        };
        if (d < HC) bcombF[d] = rd(bcomb, d);
        cbiasF[d] = rd(cbias, d);
        gwF[d] = rd(gw, d);
        gbF[d] = rd(gb, d);
        gmsF[d] = rd(gms, d);
    } else {
        int g = threadIdx.x;
        if (g > GG) return;
        int lo = 0, hi = NN;
        while (lo < hi) { int mid = (lo + hi) >> 1; if (batch[mid] < g) lo = mid + 1; else hi = mid; }
        goff[g] = lo;
    }
}

// ---------------- count edges per (chunk, range) ----------------
__global__ __launch_bounds__(256) void k_cnt(const int* ei, int* cntg) {
    __shared__ int cnt[RC];
    int c = blockIdx.x, t = threadIdx.x;
    if (t < RC) cnt[t] = 0;
    __syncthreads();
    const int* dstp = ei + EE + (size_t)c * CS;
    for (int i = t; i < CS; i += 256) atomicAdd(&cnt[dstp[i] >> RSH], 1);
    __syncthreads();
    if (t < RC) cntg[c * RC + t] = cnt[t];
}

// ---------------- per-range scan over chunks -> bucket bases ----------------
__global__ __launch_bounds__(256) void k_cscan(const int* cntg, int* baseg, int* cntr) {
    __shared__ int lds[256];
    int r = blockIdx.x, t = threadIdx.x;
    int v = cntg[t * RC + r];
    lds[t] = v;
    __syncthreads();
    for (int ofs = 1; ofs < 256; ofs <<= 1) {
        int add = (t >= ofs) ? lds[t - ofs] : 0;
        __syncthreads();
        lds[t] += add;
        __syncthreads();
    }
    baseg[t * RC + r] = r * CAP + lds[t] - v;
    if (t == 255) cntr[r] = lds[255];
}

// ---------------- prefix over ranges -> global row bases ----------------
__global__ void k_rscan(const int* cntr, int* rbase, int* row_off) {
    __shared__ int lds[128];
    int t = threadIdx.x;
    int nr = (t < RC) ? ((t == RC - 1) ? (NN - (RC - 1) * RSZ) : RSZ) : 0;
    int v = (t < RC) ? cntr[t] + nr : 0;
    lds[t] = v;
    __syncthreads();
    for (int ofs = 1; ofs < 128; ofs <<= 1) {
        int add = (t >= ofs) ? lds[t - ofs] : 0;
        __syncthreads();
        lds[t] += add;
        __syncthreads();
    }
    if (t < RC) rbase[t] = lds[t] - v;
    if (t == RC - 1) row_off[NN] = lds[t];
}

// ---------------- bucket edges by range: packed (src<<9)|dst_local ----------------
__global__ __launch_bounds__(256) void k_bucket(const int* ei, const int* baseg, unsigned* bucket) {
    __shared__ int cur[RC];
    int c = blockIdx.x, t = threadIdx.x;
    if (t < RC) cur[t] = baseg[c * RC + t];
    __syncthreads();
    const int* srcp = ei + (size_t)c * CS;
    const int* dstp = ei + EE + (size_t)c * CS;
    for (int i = t; i < CS; i += 256) {
        int d = dstp[i], s = srcp[i];
        int r = d >> RSH;
        int pos = atomicAdd(&cur[r], 1);
        bucket[pos] = ((unsigned)s << RSH) | (unsigned)(d & (RSZ - 1));
    }
}

// ---------------- per-range CSR build fully in LDS, coalesced dump ----------------
__global__ __launch_bounds__(256) void k_build(const unsigned* bucket, const int* cntr,
                                               const int* rbase, int* row_off, float* dinv,
                                               int* csr) {
    __shared__ int hist[RSZ];
    __shared__ int stage[STG];
    __shared__ int scanbuf[256];
    int r = blockIdx.x, t = threadIdx.x;
    int n0 = r * RSZ;
    int nr = NN - n0; if (nr > RSZ) nr = RSZ;
    int cr = cntr[r];
    int rb = rbase[r];
    const unsigned* bk = bucket + (size_t)r * CAP;
    #pragma unroll
    for (int j = 0; j < 2; j++) hist[t + j * 256] = 0;
    __syncthreads();
    for (int i = t; i < cr; i += 256) atomicAdd(&hist[bk[i] & (RSZ - 1)], 1);
    __syncthreads();
    // degrees incl self-loop; block scan (2 elems/thread)
    int a0 = (2 * t     < nr) ? hist[2 * t] + 1     : 0;
    int a1 = (2 * t + 1 < nr) ? hist[2 * t + 1] + 1 : 0;
    int s = a0 + a1;
    scanbuf[t] = s;
    __syncthreads();
    for (int ofs = 1; ofs < 256; ofs <<= 1) {
        int add = (t >= ofs) ? scanbuf[t - ofs] : 0;
        __syncthreads();
        scanbuf[t] += add;
        __syncthreads();
    }
    int excl = scanbuf[t] - s;
    int total = scanbuf[255];
    __syncthreads();   // all reads of hist done before cursor overwrite
    if (2 * t < nr) {
        int n = 2 * t;
        row_off[n0 + n] = rb + excl;
        dinv[n0 + n] = rsqrtf((float)a0);
        stage[excl] = n0 + n;       // self-loop slot
        hist[n] = excl + 1;         // cursor
    }
    if (2 * t + 1 < nr) {
        int n = 2 * t + 1;
        int e1 = excl + a0;
        row_off[n0 + n] = rb + e1;
        dinv[n0 + n] = rsqrtf((float)a1);
        stage[e1] = n0 + n;
        hist[n] = e1 + 1;
    }
    __syncthreads();
    for (int i = t; i < cr; i += 256) {
        unsigned p = bk[i];
        int slot = atomicAdd(&hist[p & (RSZ - 1)], 1);
        stage[slot] = (int)(p >> RSH);
    }
    __syncthreads();
    for (int i = t; i < total; i += 256) csr[rb + i] = stage[i];
}

// ---------------- pack W (bases|comb) into MFMA B-fragment layout ----------------
__global__ void k_pack(const int* flag, const void* Wb, const void* Wc, unsigned short* wpack) {
    int t = blockIdx.x, kc = blockIdx.y, lane = threadIdx.x;
    int isf = flag[0];
    int n = t * 16 + (lane & 15);
    int kb = kc * 32 + (lane >> 4) * 8;
    unsigned short* o = wpack + (size_t)(((t * KCN) + kc) * 64 + lane) * 8;
    #pragma unroll
    for (int j = 0; j < 8; j++) {
        int k = kb + j;
        int src = (n < BF) ? (k * BF + n) : (k * HC + (n - BF));
        const void* W = (n < BF) ? Wb : Wc;
        o[j] = isf ? f2b(((const float*)W)[src]) : ((const unsigned short*)W)[src];
    }
}

// ---------------- fused GEMM -> bases[N,128] bf16 + comb[N,96] f32 ----------------
__global__ __launch_bounds__(256) void k_gemm(const int* flag, const void* node,
                                              const unsigned short* wpack, const float* bcombF,
                                              unsigned short* bases, float* comb) {
    int wv = threadIdx.x >> 6, lane = threadIdx.x & 63;
    int row0 = blockIdx.x * 64 + wv * 16;
    int m = row0 + (lane & 15);
    int mc = m < NN ? m : NN - 1;
    int kg = lane >> 4;
    int isf = flag[0];
    const s16x8* bp = reinterpret_cast<const s16x8*>(wpack);
    f32x4 acc[NT];
    #pragma unroll
    for (int t = 0; t < NT; t++) acc[t] = (f32x4){0.f, 0.f, 0.f, 0.f};
    if (isf) {
        const float* nf = (const float*)node + (size_t)mc * DD;
        for (int kc = 0; kc < KCN; kc++) {
            const f32x4* src = reinterpret_cast<const f32x4*>(nf + kc * 32 + kg * 8);
            f32x4 x0 = src[0], x1 = src[1];
            union { s16x8 v; unsigned u[4]; } a;
            a.u[0] = pack_trunc(x0[0], x0[1]);
            a.u[1] = pack_trunc(x0[2], x0[3]);
            a.u[2] = pack_trunc(x1[0], x1[1]);
            a.u[3] = pack_trunc(x1[2], x1[3]);
            #pragma unroll
            for (int t = 0; t < NT; t++) {
                s16x8 b = bp[(size_t)(t * KCN + kc) * 64 + lane];
                acc[t] = __builtin_amdgcn_mfma_f32_16x16x32_bf16(a.v, b, acc[t], 0, 0, 0);
            }
        }
    } else {
        const s16x8* ap = reinterpret_cast<const s16x8*>(node);
        for (int kc = 0; kc < KCN; kc++) {
            s16x8 a = ap[(size_t)mc * 32 + kc * 4 + kg];
            #pragma unroll
            for (int t = 0; t < NT; t++) {
                s16x8 b = bp[(size_t)(t * KCN + kc) * 64 + lane];
                acc[t] = __builtin_amdgcn_mfma_f32_16x16x32_bf16(a, b, acc[t], 0, 0, 0);
            }
        }
    }
    int colb = lane & 15;
    #pragma unroll
    for (int t = 0; t < NT; t++) {
        int nc = t * 16 + colb;
        #pragma unroll
        for (int i = 0; i < 4; i++) {
            int r = row0 + kg * 4 + i;
            if (r < NN) {
                float v = acc[t][i];
                if (nc < BF) bases[(size_t)r * BF + nc] = f2b(v);
                else comb[(size_t)r * HC + (nc - BF)] = v + bcombF[nc - BF];
            }
        }
    }
}

// ---------------- per-node aggregation + einsum -> h[N,256] bf16 (ws) ----------------
__global__ __launch_bounds__(256) void k_agg(const unsigned short* bases,
                                             const float* comb, const float* dinv,
                                             const int* row_off, const int* csr,
                                             const float* cbiasF, unsigned short* h) {
    __shared__ float2 lds[4][3][64];
    int wv = threadIdx.x >> 6, lane = threadIdx.x & 63;
    int v = blockIdx.x * 4 + wv;          // NN % 4 == 0
    int r0 = row_off[v], r1 = row_off[v + 1];
    float dv = dinv[v];
    const unsigned* bp = reinterpret_cast<const unsigned*>(bases);
    float sy0 = 0.f, sy1 = 0.f, su0 = 0.f, su1 = 0.f;
    float mx0 = -3.4e38f, mx1 = -3.4e38f;
    for (int base = r0; base < r1; base += 64) {
        int nload = r1 - base; if (nload > 64) nload = 64;
        int sidx = 0; float wgt = 0.f;
        if (lane < nload) { sidx = csr[base + lane]; wgt = dinv[sidx] * dv; }
        int j = 0;
        for (; j + 4 <= nload; j += 4) {
            int s0 = __shfl(sidx, j),     s1 = __shfl(sidx, j + 1);
            int s2 = __shfl(sidx, j + 2), s3 = __shfl(sidx, j + 3);
            float w0 = __shfl(wgt, j),     w1 = __shfl(wgt, j + 1);
            float w2 = __shfl(wgt, j + 2), w3 = __shfl(wgt, j + 3);
            unsigned g0 = bp[(size_t)s0 * 64 + lane];
            unsigned g1 = bp[(size_t)s1 * 64 + lane];
            unsigned g2 = bp[(size_t)s2 * 64 + lane];
            unsigned g3 = bp[(size_t)s3 * 64 + lane];
            float a, b;
            a = b2f(g0 & 0xffffu); b = b2f(g0 >> 16);
            sy0 += w0 * a; sy1 += w0 * b; su0 += a; su1 += b; mx0 = fmaxf(mx0, a); mx1 = fmaxf(mx1, b);
            a = b2f(g1 & 0xffffu); b = b2f(g1 >> 16);
            sy0 += w1 * a; sy1 += w1 * b; su0 += a; su1 += b; mx0 = fmaxf(mx0, a); mx1 = fmaxf(mx1, b);
            a = b2f(g2 & 0xffffu); b = b2f(g2 >> 16);
            sy0 += w2 * a; sy1 += w2 * b; su0 += a; su1 += b; mx0 = fmaxf(mx0, a); mx1 = fmaxf(mx1, b);
            a = b2f(g3 & 0xffffu); b = b2f(g3 >> 16);
            sy0 += w3 * a; sy1 += w3 * b; su0 += a; su1 += b; mx0 = fmaxf(mx0, a); mx1 = fmaxf(mx1, b);
        }
        for (; j < nload; j++) {
            int s0 = __shfl(sidx, j); float w0 = __shfl(wgt, j);
            unsigned g0 = bp[(size_t)s0 * 64 + lane];
            float a = b2f(g0 & 0xffffu), b = b2f(g0 >> 16);
            sy0 += w0 * a; sy1 += w0 * b; su0 += a; su1 += b; mx0 = fmaxf(mx0, a); mx1 = fmaxf(mx1, b);
        }
    }
    lds[wv][0][lane] = (float2){sy0, sy1};
    lds[wv][1][lane] = (float2){su0, su1};
    lds[wv][2][lane] = (float2){mx0, mx1};
    __syncthreads();
    const float* P0 = (const float*)&lds[wv][0][0];
    const float* P1 = (const float*)&lds[wv][1][0];
    const float* P2 = (const float*)&lds[wv][2][0];
    int d0 = lane * 4;
    int hh = d0 >> 5;
    float cb[12];
    #pragma unroll
    for (int k = 0; k < 12; k++) cb[k] = comb[(size_t)v * HC + hh * 12 + k];
    union { unsigned short e[4]; uint2 u; } o;
    #pragma unroll
    for (int i = 0; i < 4; i++) {
        int d = d0 + i, f = d & 31;
        float acc = cbiasF[d];
        #pragma unroll
        for (int k = 0; k < 12; k++) {
            int a = k >> 2, b = k & 3;
            const float* P = (a == 0) ? P0 : ((a == 1) ? P1 : P2);
            acc += cb[k] * P[b * 32 + f];
        }
        o.e[i] = f2b(acc);
    }
    reinterpret_cast<uint2*>(h)[(size_t)v * 64 + lane] = o.u;
}

// ---------------- GraphNorm stats pass 1: atomic-free sliced reduction ----------------
__global__ void k_stats1(const unsigned short* h, const int* goff, float* sstat) {
    int g = blockIdx.x, s = blockIdx.y, t = threadIdx.x;
    int v0 = goff[g], v1 = goff[g + 1];
    float sum = 0.f, sq = 0.f;
    for (int v = v0 + s; v < v1; v += SL) {
        float x = b2f(h[(size_t)v * DD + t]);
        sum += x; sq += x * x;
    }
    size_t o = ((size_t)(g * SL + s)) * (2 * DD);
    sstat[o + t] = sum;
    sstat[o + DD + t] = sq;
}

// ---------------- GraphNorm stats pass 2 ----------------
__global__ void k_stats2(const float* sstat, const int* goff,
                         const float* gwF, const float* gbF, const float* gmsF,
                         float* sA, float* sB) {
    int g = blockIdx.x, d = threadIdx.x;
    float sum = 0.f, sq = 0.f;
    #pragma unroll
    for (int s = 0; s < SL; s++) {
        size_t o = ((size_t)(g * SL + s)) * (2 * DD);
        sum += sstat[o + d];
        sq  += sstat[o + DD + d];
    }
    int c = goff[g + 1] - goff[g];
    float cnt = (float)(c > 1 ? c : 1);
    float mu = sum / cnt;
    float m2 = sq / cnt;
    float al = gmsF[d];
    float var = m2 - mu * mu * (2.f * al - al * al);   // E[(h-al*mu)^2]
    float rstd = rsqrtf(var + 1e-5f);
    float sa = gwF[d] * rstd;
    sA[g * DD + d] = sa;
    sB[g * DD + d] = gbF[d] - sa * al * mu;
}

// ---------------- final normalize + ReLU -> d_out ----------------
__global__ void k_out(const int* flag, const unsigned short* h, const int* batch,
                      const float* sA, const float* sB, void* out) {
    int tid = blockIdx.x * 256 + threadIdx.x;
    int v = tid >> 6, q = tid & 63;
    if (v >= NN) return;
    int g = batch[v];
    uint2 xr = reinterpret_cast<const uint2*>(h)[(size_t)v * 64 + q];
    f32x4 a = reinterpret_cast<const f32x4*>(sA)[g * 64 + q];
    f32x4 b = reinterpret_cast<const f32x4*>(sB)[g * 64 + q];
    float x0 = b2f(xr.x & 0xffffu), x1 = b2f(xr.x >> 16);
    float x2 = b2f(xr.y & 0xffffu), x3 = b2f(xr.y >> 16);
    float y0 = fmaxf(x0 * a[0] + b[0], 0.f);
    float y1 = fmaxf(x1 * a[1] + b[1], 0.f);
    float y2 = fmaxf(x2 * a[2] + b[2], 0.f);
    float y3 = fmaxf(x3 * a[3] + b[3], 0.f);
    if (flag[0]) {
        f32x4 y = {y0, y1, y2, y3};
        reinterpret_cast<f32x4*>(out)[(size_t)v * 64 + q] = y;
    } else {
        union { unsigned short e[4]; uint2 u; } o;
        o.e[0] = f2b(y0); o.e[1] = f2b(y1); o.e[2] = f2b(y2); o.e[3] = f2b(y3);
        reinterpret_cast<uint2*>(out)[(size_t)v * 64 + q] = o.u;
    }
}

extern "C" void kernel_launch(void* const* d_in, const int* in_sizes, int n_in,
                              void* d_out, int out_size, void* d_ws, size_t ws_size,
                              hipStream_t stream) {
    const void* node  = d_in[0];
    const void* Wb    = d_in[2];
    const void* Wc    = d_in[3];
    const void* bcomb = d_in[4];
    const void* cbias = d_in[5];
    const void* gw    = d_in[6];
    const void* gb    = d_in[7];
    const void* gms   = d_in[8];
    const int* ei     = (const int*)d_in[9];
    const int* batch  = (const int*)d_in[10];

    char* w = (char*)d_ws;
    size_t off = 0;
    auto alloc = [&](size_t bytes) -> void* {
        off = (off + 255) & ~(size_t)255;
        void* p = w + off;
        off += bytes;
        return p;
    };
    unsigned short* bases = (unsigned short*)alloc((size_t)NN * BF * 2);
    float* comb    = (float*)alloc((size_t)NN * HC * 4);
    unsigned short* h = (unsigned short*)alloc((size_t)NN * DD * 2);
    int*   csr     = (int*)alloc((size_t)(EE + NN) * 4);
    unsigned* bucket = (unsigned*)alloc((size_t)RC * CAP * 4);
    int*   cntg    = (int*)alloc((size_t)CC * RC * 4);
    int*   baseg   = (int*)alloc((size_t)CC * RC * 4);
    int*   cntrr   = (int*)alloc((size_t)RC * 4);
    int*   rbase   = (int*)alloc((size_t)RC * 4);
    float* dinv    = (float*)alloc((size_t)NN * 4);
    int*   row_off = (int*)alloc((size_t)(NN + 1) * 4);
    int*   goff    = (int*)alloc((size_t)(GG + 1) * 4);
    float* sstat   = (float*)alloc((size_t)GG * SL * 2 * DD * 4);
    float* sA      = (float*)alloc((size_t)GG * DD * 4);
    float* sB      = (float*)alloc((size_t)GG * DD * 4);
    unsigned short* wpack = (unsigned short*)alloc((size_t)NT * KCN * 64 * 8 * 2);
    int*   flag    = (int*)alloc(256);
    float* bcombF  = (float*)alloc(HC * 4);
    float* cbiasF  = (float*)alloc(DD * 4);
    float* gwF     = (float*)alloc(DD * 4);
    float* gbF     = (float*)alloc(DD * 4);
    float* gmsF    = (float*)alloc(DD * 4);

    k_setup<<<2, 256, 0, stream>>>((const unsigned short*)node, flag, bcomb, cbias, gw, gb, gms,
                                   bcombF, cbiasF, gwF, gbF, gmsF, batch, goff);
    k_cnt<<<CC, 256, 0, stream>>>(ei, cntg);
    k_cscan<<<RC, 256, 0, stream>>>(cntg, baseg, cntrr);
    k_rscan<<<1, 128, 0, stream>>>(cntrr, rbase, row_off);
    k_bucket<<<CC, 256, 0, stream>>>(ei, baseg, bucket);
    k_build<<<RC, 256, 0, stream>>>(bucket, cntrr, rbase, row_off, dinv, csr);
    k_pack<<<dim3(NT, KCN), 64, 0, stream>>>(flag, Wb, Wc, wpack);
    k_gemm<<<(NN + 63) / 64, 256, 0, stream>>>(flag, node, wpack, bcombF, bases, comb);
    k_agg<<<NN / 4, 256, 0, stream>>>(bases, comb, dinv, row_off, csr, cbiasF, h);
    k_stats1<<<dim3(GG, SL), 256, 0, stream>>>(h, goff, sstat);
    k_stats2<<<GG, 256, 0, stream>>>(sstat, goff, gwF, gbF, gmsF, sA, sB);
    k_out<<<(NN * 64 + 255) / 256, 256, 0, stream>>>(flag, h, batch, sA, sB, d_out);
}

// Round 8
// 267.922 us; speedup vs baseline: 1.1685x; 1.0122x over previous
//
#include <hip/hip_runtime.h>
#include <hip/hip_bf16.h>

#define NN 50000
#define EE 800000
#define DD 256
#define BF 128      // B*F
#define HC 96       // H*B*A
#define GG 64
#define NT 14       // (BF+HC)/16
#define KCN 8       // 256/32 k-chunks
#define RC 98       // node ranges (512 nodes each)
#define RSH 9       // range shift: RS = 512
#define RSZ 512
#define CC 256      // edge chunks
#define CS 3125     // edges per chunk (EE/256)
#define CAP 10240   // bucket capacity per range (avg 8192)
#define SL 16       // stats slices per graph
#define STG 10752   // CAP + RSZ

typedef short s16x8 __attribute__((ext_vector_type(8)));
typedef float f32x4 __attribute__((ext_vector_type(4)));

static __device__ __forceinline__ float b2f(unsigned u) {
    unsigned x = u << 16;
    float f;
    __builtin_memcpy(&f, &x, 4);
    return f;
}
static __device__ __forceinline__ unsigned short f2b(float f) {
    unsigned x;
    __builtin_memcpy(&x, &f, 4);
    unsigned lsb = (x >> 16) & 1u;
    x += 0x7fffu + lsb;           // round-to-nearest-even
    return (unsigned short)(x >> 16);
}
static __device__ __forceinline__ unsigned pack_trunc(float lo, float hi) {
    unsigned ulo, uhi;
    __builtin_memcpy(&ulo, &lo, 4);
    __builtin_memcpy(&uhi, &hi, 4);
    return (ulo >> 16) | (uhi & 0xffff0000u);
}

// ---------------- setup: dtype detect + param convert + goff ----------------
__global__ void k_setup(const unsigned short* node_u16, int* flag,
                        const void* bcomb, const void* cbias, const void* gw,
                        const void* gb, const void* gms,
                        float* bcombF, float* cbiasF, float* gwF, float* gbF, float* gmsF,
                        const int* batch, int* goff) {
    if (blockIdx.x == 0) {
        __shared__ int cnt;
        if (threadIdx.x == 0) cnt = 0;
        __syncthreads();
        int local = 0;
        #pragma unroll
        for (int j = 0; j < 4; j++) {
            int idx = 2 * (threadIdx.x * 4 + j);   // EVEN u16 of f32 = mantissa garbage
            unsigned short u = node_u16[idx];
            int e = (u >> 7) & 0xFF;
            if (e < 100 || e > 140) local++;
        }
        atomicAdd(&cnt, local);
        __syncthreads();
        int isf = (cnt > 256) ? 1 : 0;
        if (threadIdx.x == 0) flag[0] = isf;
        int d = threadIdx.x;
        auto rd = [&](const void* p, int i) -> float {
            return isf ? ((const float*)p)[i] : b2f(((const unsigned short*)p)[i]);
        };
        if (d < HC) bcombF[d] = rd(bcomb, d);
        cbiasF[d] = rd(cbias, d);
        gwF[d] = rd(gw, d);
        gbF[d] = rd(gb, d);
        gmsF[d] = rd(gms, d);
    } else {
        int g = threadIdx.x;
        if (g > GG) return;
        int lo = 0, hi = NN;
        while (lo < hi) { int mid = (lo + hi) >> 1; if (batch[mid] < g) lo = mid + 1; else hi = mid; }
        goff[g] = lo;
    }
}

// ---------------- count edges per (chunk, range) ----------------
__global__ __launch_bounds__(256) void k_cnt(const int* ei, int* cntg) {
    __shared__ int cnt[RC];
    int c = blockIdx.x, t = threadIdx.x;
    if (t < RC) cnt[t] = 0;
    __syncthreads();
    const int* dstp = ei + EE + (size_t)c * CS;
    for (int i = t; i < CS; i += 256) atomicAdd(&cnt[dstp[i] >> RSH], 1);
    __syncthreads();
    if (t < RC) cntg[c * RC + t] = cnt[t];
}

// ---------------- per-range scan over chunks -> bucket bases ----------------
__global__ __launch_bounds__(256) void k_cscan(const int* cntg, int* baseg, int* cntr) {
    __shared__ int lds[256];
    int r = blockIdx.x, t = threadIdx.x;
    int v = cntg[t * RC + r];
    lds[t] = v;
    __syncthreads();
    for (int ofs = 1; ofs < 256; ofs <<= 1) {
        int add = (t >= ofs) ? lds[t - ofs] : 0;
        __syncthreads();
        lds[t] += add;
        __syncthreads();
    }
    baseg[t * RC + r] = r * CAP + lds[t] - v;
    if (t == 255) cntr[r] = lds[255];
}

// ---------------- prefix over ranges -> global row bases ----------------
__global__ void k_rscan(const int* cntr, int* rbase, int* row_off) {
    __shared__ int lds[128];
    int t = threadIdx.x;
    int nr = (t < RC) ? ((t == RC - 1) ? (NN - (RC - 1) * RSZ) : RSZ) : 0;
    int v = (t < RC) ? cntr[t] + nr : 0;
    lds[t] = v;
    __syncthreads();
    for (int ofs = 1; ofs < 128; ofs <<= 1) {
        int add = (t >= ofs) ? lds[t - ofs] : 0;
        __syncthreads();
        lds[t] += add;
        __syncthreads();
    }
    if (t < RC) rbase[t] = lds[t] - v;
    if (t == RC - 1) row_off[NN] = lds[t];
}

// ---------------- bucket edges by range: packed (src<<9)|dst_local ----------------
__global__ __launch_bounds__(256) void k_bucket(const int* ei, const int* baseg, unsigned* bucket) {
    __shared__ int cur[RC];
    int c = blockIdx.x, t = threadIdx.x;
    if (t < RC) cur[t] = baseg[c * RC + t];
    __syncthreads();
    const int* srcp = ei + (size_t)c * CS;
    const int* dstp = ei + EE + (size_t)c * CS;
    for (int i = t; i < CS; i += 256) {
        int d = dstp[i], s = srcp[i];
        int r = d >> RSH;
        int pos = atomicAdd(&cur[r], 1);
        bucket[pos] = ((unsigned)s << RSH) | (unsigned)(d & (RSZ - 1));
    }
}

// ---------------- per-range CSR build fully in LDS, coalesced dump ----------------
__global__ __launch_bounds__(256) void k_build(const unsigned* bucket, const int* cntr,
                                               const int* rbase, int* row_off, float* dinv,
                                               int* csr) {
    __shared__ int hist[RSZ];
    __shared__ int stage[STG];
    __shared__ int scanbuf[256];
    int r = blockIdx.x, t = threadIdx.x;
    int n0 = r * RSZ;
    int nr = NN - n0; if (nr > RSZ) nr = RSZ;
    int cr = cntr[r];
    int rb = rbase[r];
    const unsigned* bk = bucket + (size_t)r * CAP;
    #pragma unroll
    for (int j = 0; j < 2; j++) hist[t + j * 256] = 0;
    __syncthreads();
    for (int i = t; i < cr; i += 256) atomicAdd(&hist[bk[i] & (RSZ - 1)], 1);
    __syncthreads();
    int a0 = (2 * t     < nr) ? hist[2 * t] + 1     : 0;
    int a1 = (2 * t + 1 < nr) ? hist[2 * t + 1] + 1 : 0;
    int s = a0 + a1;
    scanbuf[t] = s;
    __syncthreads();
    for (int ofs = 1; ofs < 256; ofs <<= 1) {
        int add = (t >= ofs) ? scanbuf[t - ofs] : 0;
        __syncthreads();
        scanbuf[t] += add;
        __syncthreads();
    }
    int excl = scanbuf[t] - s;
    int total = scanbuf[255];
    __syncthreads();
    if (2 * t < nr) {
        int n = 2 * t;
        row_off[n0 + n] = rb + excl;
        dinv[n0 + n] = rsqrtf((float)a0);
        stage[excl] = n0 + n;
        hist[n] = excl + 1;
    }
    if (2 * t + 1 < nr) {
        int n = 2 * t + 1;
        int e1 = excl + a0;
        row_off[n0 + n] = rb + e1;
        dinv[n0 + n] = rsqrtf((float)a1);
        stage[e1] = n0 + n;
        hist[n] = e1 + 1;
    }
    __syncthreads();
    for (int i = t; i < cr; i += 256) {
        unsigned p = bk[i];
        int slot = atomicAdd(&hist[p & (RSZ - 1)], 1);
        stage[slot] = (int)(p >> RSH);
    }
    __syncthreads();
    for (int i = t; i < total; i += 256) csr[rb + i] = stage[i];
}

// ---------------- pack W (bases|comb) into MFMA B-fragment layout ----------------
__global__ void k_pack(const int* flag, const void* Wb, const void* Wc, unsigned short* wpack) {
    int t = blockIdx.x, kc = blockIdx.y, lane = threadIdx.x;
    int isf = flag[0];
    int n = t * 16 + (lane & 15);
    int kb = kc * 32 + (lane >> 4) * 8;
    unsigned short* o = wpack + (size_t)(((t * KCN) + kc) * 64 + lane) * 8;
    #pragma unroll
    for (int j = 0; j < 8; j++) {
        int k = kb + j;
        int src = (n < BF) ? (k * BF + n) : (k * HC + (n - BF));
        const void* W = (n < BF) ? Wb : Wc;
        o[j] = isf ? f2b(((const float*)W)[src]) : ((const unsigned short*)W)[src];
    }
}

// ---------------- fused GEMM, 2-wave col-split: low VGPR, deep MLP ----------------
// block = 128 threads (2 waves); wave w owns col-tiles w*7..w*7+6; block = 16 rows.
__global__ __launch_bounds__(128) void k_gemm(const int* flag, const void* node,
                                              const unsigned short* wpack, const float* bcombF,
                                              unsigned short* bases, float* comb) {
    int wv = threadIdx.x >> 6, lane = threadIdx.x & 63;
    int m = blockIdx.x * 16 + (lane & 15);   // 3125*16 == NN exactly
    int kg = lane >> 4;
    int isf = flag[0];
    const s16x8* bp = reinterpret_cast<const s16x8*>(wpack);
    f32x4 acc[7];
    #pragma unroll
    for (int t = 0; t < 7; t++) acc[t] = (f32x4){0.f, 0.f, 0.f, 0.f};
    if (isf) {
        const float* nf = (const float*)node + (size_t)m * DD;
        for (int kc = 0; kc < KCN; kc++) {
            const f32x4* src = reinterpret_cast<const f32x4*>(nf + kc * 32 + kg * 8);
            f32x4 x0 = src[0], x1 = src[1];
            union { s16x8 v; unsigned u[4]; } a;
            a.u[0] = pack_trunc(x0[0], x0[1]);
            a.u[1] = pack_trunc(x0[2], x0[3]);
            a.u[2] = pack_trunc(x1[0], x1[1]);
            a.u[3] = pack_trunc(x1[2], x1[3]);
            #pragma unroll
            for (int t2 = 0; t2 < 7; t2++) {
                int t = wv * 7 + t2;
                s16x8 b = bp[(size_t)(t * KCN + kc) * 64 + lane];
                acc[t2] = __builtin_amdgcn_mfma_f32_16x16x32_bf16(a.v, b, acc[t2], 0, 0, 0);
            }
        }
    } else {
        const s16x8* ap = reinterpret_cast<const s16x8*>(node);
        for (int kc = 0; kc < KCN; kc++) {
            s16x8 a = ap[(size_t)m * 32 + kc * 4 + kg];
            #pragma unroll
            for (int t2 = 0; t2 < 7; t2++) {
                int t = wv * 7 + t2;
                s16x8 b = bp[(size_t)(t * KCN + kc) * 64 + lane];
                acc[t2] = __builtin_amdgcn_mfma_f32_16x16x32_bf16(a, b, acc[t2], 0, 0, 0);
            }
        }
    }
    int colb = lane & 15;
    int row0 = blockIdx.x * 16;
    #pragma unroll
    for (int t2 = 0; t2 < 7; t2++) {
        int nc = (wv * 7 + t2) * 16 + colb;
        #pragma unroll
        for (int i = 0; i < 4; i++) {
            int r = row0 + kg * 4 + i;
            float v = acc[t2][i];
            if (nc < BF) bases[(size_t)r * BF + nc] = f2b(v);
            else comb[(size_t)r * HC + (nc - BF)] = v + bcombF[nc - BF];
        }
    }
}

// ---------------- per-node aggregation + einsum -> h[N,256] bf16 (ws) ----------------
__global__ __launch_bounds__(256) void k_agg(const unsigned short* bases,
                                             const float* comb, const float* dinv,
                                             const int* row_off, const int* csr,
                                             const float* cbiasF, unsigned short* h) {
    __shared__ float2 lds[4][3][64];
    int wv = threadIdx.x >> 6, lane = threadIdx.x & 63;
    int v = blockIdx.x * 4 + wv;          // NN % 4 == 0
    int r0 = row_off[v], r1 = row_off[v + 1];
    float dv = dinv[v];
    const unsigned* bp = reinterpret_cast<const unsigned*>(bases);
    float sy0 = 0.f, sy1 = 0.f, su0 = 0.f, su1 = 0.f;
    float mx0 = -3.4e38f, mx1 = -3.4e38f;
    for (int base = r0; base < r1; base += 64) {
        int nload = r1 - base; if (nload > 64) nload = 64;
        int sidx = 0; float wgt = 0.f;
        if (lane < nload) { sidx = csr[base + lane]; wgt = dinv[sidx] * dv; }
        int j = 0;
        for (; j + 8 <= nload; j += 8) {
            int ss[8]; float ww[8]; unsigned gg[8];
            #pragma unroll
            for (int k = 0; k < 8; k++) { ss[k] = __shfl(sidx, j + k); ww[k] = __shfl(wgt, j + k); }
            #pragma unroll
            for (int k = 0; k < 8; k++) gg[k] = bp[(size_t)ss[k] * 64 + lane];
            #pragma unroll
            for (int k = 0; k < 8; k++) {
                float a = b2f(gg[k] & 0xffffu), b = b2f(gg[k] >> 16);
                sy0 += ww[k] * a; sy1 += ww[k] * b;
                su0 += a; su1 += b;
                mx0 = fmaxf(mx0, a); mx1 = fmaxf(mx1, b);
            }
        }
        for (; j < nload; j++) {
            int s0 = __shfl(sidx, j); float w0 = __shfl(wgt, j);
            unsigned g0 = bp[(size_t)s0 * 64 + lane];
            float a = b2f(g0 & 0xffffu), b = b2f(g0 >> 16);
            sy0 += w0 * a; sy1 += w0 * b; su0 += a; su1 += b; mx0 = fmaxf(mx0, a); mx1 = fmaxf(mx1, b);
        }
    }
    lds[wv][0][lane] = (float2){sy0, sy1};
    lds[wv][1][lane] = (float2){su0, su1};
    lds[wv][2][lane] = (float2){mx0, mx1};
    __syncthreads();
    const float* P0 = (const float*)&lds[wv][0][0];
    const float* P1 = (const float*)&lds[wv][1][0];
    const float* P2 = (const float*)&lds[wv][2][0];
    int d0 = lane * 4;
    int hh = d0 >> 5;
    float cb[12];
    #pragma unroll
    for (int k = 0; k < 12; k++) cb[k] = comb[(size_t)v * HC + hh * 12 + k];
    union { unsigned short e[4]; uint2 u; } o;
    #pragma unroll
    for (int i = 0; i < 4; i++) {
        int d = d0 + i, f = d & 31;
        float acc = cbiasF[d];
        #pragma unroll
        for (int k = 0; k < 12; k++) {
            int a = k >> 2, b = k & 3;
            const float* P = (a == 0) ? P0 : ((a == 1) ? P1 : P2);
            acc += cb[k] * P[b * 32 + f];
        }
        o.e[i] = f2b(acc);
    }
    reinterpret_cast<uint2*>(h)[(size_t)v * 64 + lane] = o.u;
}

// ---------------- GraphNorm stats pass 1: atomic-free, u32 loads ----------------
__global__ __launch_bounds__(128) void k_stats1(const unsigned short* h, const int* goff, float* sstat) {
    int g = blockIdx.x, s = blockIdx.y, t = threadIdx.x;   // t < 128 -> col pair
    int v0 = goff[g], v1 = goff[g + 1];
    const unsigned* hu = reinterpret_cast<const unsigned*>(h);
    float s0 = 0.f, s1 = 0.f, q0 = 0.f, q1 = 0.f;
    for (int v = v0 + s; v < v1; v += SL) {
        unsigned x = hu[(size_t)v * 128 + t];
        float a = b2f(x & 0xffffu), b = b2f(x >> 16);
        s0 += a; s1 += b; q0 += a * a; q1 += b * b;
    }
    size_t o = ((size_t)(g * SL + s)) * (2 * DD);
    sstat[o + 2 * t] = s0;
    sstat[o + 2 * t + 1] = s1;
    sstat[o + DD + 2 * t] = q0;
    sstat[o + DD + 2 * t + 1] = q1;
}

// ---------------- GraphNorm stats pass 2 ----------------
__global__ void k_stats2(const float* sstat, const int* goff,
                         const float* gwF, const float* gbF, const float* gmsF,
                         float* sA, float* sB) {
    int g = blockIdx.x, d = threadIdx.x;
    float sum = 0.f, sq = 0.f;
    for (int s = 0; s < SL; s++) {
        size_t o = ((size_t)(g * SL + s)) * (2 * DD);
        sum += sstat[o + d];
        sq  += sstat[o + DD + d];
    }
    int c = goff[g + 1] - goff[g];
    float cnt = (float)(c > 1 ? c : 1);
    float mu = sum / cnt;
    float m2 = sq / cnt;
    float al = gmsF[d];
    float var = m2 - mu * mu * (2.f * al - al * al);   // E[(h-al*mu)^2]
    float rstd = rsqrtf(var + 1e-5f);
    float sa = gwF[d] * rstd;
    sA[g * DD + d] = sa;
    sB[g * DD + d] = gbF[d] - sa * al * mu;
}

// ---------------- final normalize + ReLU -> d_out ----------------
__global__ void k_out(const int* flag, const unsigned short* h, const int* batch,
                      const float* sA, const float* sB, void* out) {
    int tid = blockIdx.x * 256 + threadIdx.x;
    int v = tid >> 6, q = tid & 63;
    if (v >= NN) return;
    int g = batch[v];
    uint2 xr = reinterpret_cast<const uint2*>(h)[(size_t)v * 64 + q];
    f32x4 a = reinterpret_cast<const f32x4*>(sA)[g * 64 + q];
    f32x4 b = reinterpret_cast<const f32x4*>(sB)[g * 64 + q];
    float x0 = b2f(xr.x & 0xffffu), x1 = b2f(xr.x >> 16);
    float x2 = b2f(xr.y & 0xffffu), x3 = b2f(xr.y >> 16);
    float y0 = fmaxf(x0 * a[0] + b[0], 0.f);
    float y1 = fmaxf(x1 * a[1] + b[1], 0.f);
    float y2 = fmaxf(x2 * a[2] + b[2], 0.f);
    float y3 = fmaxf(x3 * a[3] + b[3], 0.f);
    if (flag[0]) {
        f32x4 y = {y0, y1, y2, y3};
        reinterpret_cast<f32x4*>(out)[(size_t)v * 64 + q] = y;
    } else {
        union { unsigned short e[4]; uint2 u; } o;
        o.e[0] = f2b(y0); o.e[1] = f2b(y1); o.e[2] = f2b(y2); o.e[3] = f2b(y3);
        reinterpret_cast<uint2*>(out)[(size_t)v * 64 + q] = o.u;
    }
}

extern "C" void kernel_launch(void* const* d_in, const int* in_sizes, int n_in,
                              void* d_out, int out_size, void* d_ws, size_t ws_size,
                              hipStream_t stream) {
    const void* node  = d_in[0];
    const void* Wb    = d_in[2];
    const void* Wc    = d_in[3];
    const void* bcomb = d_in[4];
    const void* cbias = d_in[5];
    const void* gw    = d_in[6];
    const void* gb    = d_in[7];
    const void* gms   = d_in[8];
    const int* ei     = (const int*)d_in[9];
    const int* batch  = (const int*)d_in[10];

    char* w = (char*)d_ws;
    size_t off = 0;
    auto alloc = [&](size_t bytes) -> void* {
        off = (off + 255) & ~(size_t)255;
        void* p = w + off;
        off += bytes;
        return p;
    };
    unsigned short* bases = (unsigned short*)alloc((size_t)NN * BF * 2);
    float* comb    = (float*)alloc((size_t)NN * HC * 4);
    unsigned short* h = (unsigned short*)alloc((size_t)NN * DD * 2);
    int*   csr     = (int*)alloc((size_t)(EE + NN) * 4);
    unsigned* bucket = (unsigned*)alloc((size_t)RC * CAP * 4);
    int*   cntg    = (int*)alloc((size_t)CC * RC * 4);
    int*   baseg   = (int*)alloc((size_t)CC * RC * 4);
    int*   cntrr   = (int*)alloc((size_t)RC * 4);
    int*   rbase   = (int*)alloc((size_t)RC * 4);
    float* dinv    = (float*)alloc((size_t)NN * 4);
    int*   row_off = (int*)alloc((size_t)(NN + 1) * 4);
    int*   goff    = (int*)alloc((size_t)(GG + 1) * 4);
    float* sstat   = (float*)alloc((size_t)GG * SL * 2 * DD * 4);
    float* sA      = (float*)alloc((size_t)GG * DD * 4);
    float* sB      = (float*)alloc((size_t)GG * DD * 4);
    unsigned short* wpack = (unsigned short*)alloc((size_t)NT * KCN * 64 * 8 * 2);
    int*   flag    = (int*)alloc(256);
    float* bcombF  = (float*)alloc(HC * 4);
    float* cbiasF  = (float*)alloc(DD * 4);
    float* gwF     = (float*)alloc(DD * 4);
    float* gbF     = (float*)alloc(DD * 4);
    float* gmsF    = (float*)alloc(DD * 4);

    k_setup<<<2, 256, 0, stream>>>((const unsigned short*)node, flag, bcomb, cbias, gw, gb, gms,
                                   bcombF, cbiasF, gwF, gbF, gmsF, batch, goff);
    k_cnt<<<CC, 256, 0, stream>>>(ei, cntg);
    k_cscan<<<RC, 256, 0, stream>>>(cntg, baseg, cntrr);
    k_rscan<<<1, 128, 0, stream>>>(cntrr, rbase, row_off);
    k_bucket<<<CC, 256, 0, stream>>>(ei, baseg, bucket);
    k_build<<<RC, 256, 0, stream>>>(bucket, cntrr, rbase, row_off, dinv, csr);
    k_pack<<<dim3(NT, KCN), 64, 0, stream>>>(flag, Wb, Wc, wpack);
    k_gemm<<<NN / 16, 128, 0, stream>>>(flag, node, wpack, bcombF, bases, comb);
    k_agg<<<NN / 4, 256, 0, stream>>>(bases, comb, dinv, row_off, csr, cbiasF, h);
    k_stats1<<<dim3(GG, SL), 128, 0, stream>>>(h, goff, sstat);
    k_stats2<<<GG, 256, 0, stream>>>(sstat, goff, gwF, gbF, gmsF, sA, sB);
    k_out<<<(NN * 64 + 255) / 256, 256, 0, stream>>>(flag, h, batch, sA, sB, d_out);
}